// Round 1
// baseline (389.118 us; speedup 1.0000x reference)
//
#include <hip/hip_runtime.h>
#include <math.h>

#define BB 4
#define CC 64
#define HID 32
#define NN 4096   // 64*64 spatial
#define PAD 36    // HID+4: keeps rows 16B-aligned, conflict-free float4 reads

// ---------------------------------------------------------------------------
// Kernel A: QKV projection.  q/k/v[b][n][HID] = W @ x[b][:,n] + bias
// ---------------------------------------------------------------------------
__global__ __launch_bounds__(256) void qkv_kernel(
    const float* __restrict__ x,
    const float* __restrict__ wq, const float* __restrict__ bq,
    const float* __restrict__ wk, const float* __restrict__ bk,
    const float* __restrict__ wv, const float* __restrict__ bv,
    float* __restrict__ q, float* __restrict__ k, float* __restrict__ v)
{
    __shared__ float xs[CC][64];        // x[c][j] tile
    __shared__ float ws[3*HID][CC+1];   // wq|wk|wv, +1 pad: bank=(row+c)%32
    __shared__ float bs[3*HID];

    const int t  = threadIdx.x;
    const int b  = blockIdx.x >> 6;
    const int n0 = (blockIdx.x & 63) << 6;

    for (int i = t; i < CC*64; i += 256) {
        int c = i >> 6, j = i & 63;
        xs[c][j] = x[(b*CC + c) * NN + n0 + j];
    }
    for (int i = t; i < HID*CC; i += 256) {
        int h = i >> 6, c = i & 63;
        ws[h][c]         = wq[i];
        ws[HID + h][c]   = wk[i];
        ws[2*HID + h][c] = wv[i];
    }
    if (t < HID) { bs[t] = bq[t]; bs[HID + t] = bk[t]; bs[2*HID + t] = bv[t]; }
    __syncthreads();

    const int h  = t & 31;   // hid index
    const int jb = t >> 5;   // 0..7
    for (int m = 0; m < 3; ++m) {
        float* outp = (m == 0) ? q : (m == 1) ? k : v;
        const float bias = bs[m*HID + h];
        for (int jj = 0; jj < 8; ++jj) {
            int j = jb + 8*jj;
            float s = bias;
            #pragma unroll
            for (int c = 0; c < CC; ++c) s += ws[m*HID + h][c] * xs[c][j];
            outp[((size_t)(b*NN) + n0 + j) * HID + h] = s;
        }
    }
}

// ---------------------------------------------------------------------------
// Kernel B: fused flash attention + output projection + residual.
// Block = 64 queries (one batch), 512 threads = 64 q x 8 key-groups.
// ---------------------------------------------------------------------------
__global__ __launch_bounds__(512) void attn_kernel(
    const float* __restrict__ q, const float* __restrict__ k,
    const float* __restrict__ v, const float* __restrict__ x,
    const float* __restrict__ wp, const float* __restrict__ bp,
    float* __restrict__ out)
{
    __shared__ float qs[64][PAD];
    __shared__ float ks[64][PAD];
    __shared__ float vs[64][PAD];
    __shared__ float zs[64][PAD];
    __shared__ float wps[CC][HID];   // broadcast access (uniform c per wave)
    __shared__ float bps[CC];

    const int t  = threadIdx.x;
    const int b  = blockIdx.x >> 6;
    const int q0 = (blockIdx.x & 63) << 6;

    for (int i = t; i < 64*HID; i += 512)
        qs[i >> 5][i & 31] = q[((size_t)(b*NN) + q0) * HID + i];
    for (int i = t; i < CC*HID; i += 512)
        wps[i >> 5][i & 31] = wp[i];
    if (t < CC) bps[t] = bp[t];
    __syncthreads();

    const int myq = t >> 3;   // 0..63
    const int kg  = t & 7;    // 0..7

    // Q row in registers
    float qf[HID];
    #pragma unroll
    for (int d4 = 0; d4 < HID/4; ++d4) {
        float4 qv = *(const float4*)&qs[myq][4*d4];
        qf[4*d4+0] = qv.x; qf[4*d4+1] = qv.y; qf[4*d4+2] = qv.z; qf[4*d4+3] = qv.w;
    }

    float m = -1e30f, l = 0.f;
    float acc[HID];
    #pragma unroll
    for (int d = 0; d < HID; ++d) acc[d] = 0.f;

    for (int kt = 0; kt < NN/64; ++kt) {
        __syncthreads();
        for (int i = t; i < 64*HID; i += 512) {
            int r = i >> 5, c = i & 31;
            size_t g = ((size_t)(b*NN) + kt*64) * HID + i;
            ks[r][c] = k[g];
            vs[r][c] = v[g];
        }
        __syncthreads();

        float s[8];
        float tmax = -1e30f;
        #pragma unroll
        for (int kk = 0; kk < 8; ++kk) {
            int j = kg + 8*kk;   // 8 distinct j per wave -> conflict-free
            const float4* ksr = (const float4*)&ks[j][0];
            float sc = 0.f;
            #pragma unroll
            for (int d4 = 0; d4 < HID/4; ++d4) {
                float4 kv = ksr[d4];
                sc += qf[4*d4+0]*kv.x + qf[4*d4+1]*kv.y
                    + qf[4*d4+2]*kv.z + qf[4*d4+3]*kv.w;
            }
            s[kk] = sc;
            tmax = fmaxf(tmax, sc);
        }

        float mnew  = fmaxf(m, tmax);
        float scale = __expf(m - mnew);
        l *= scale;
        #pragma unroll
        for (int d = 0; d < HID; ++d) acc[d] *= scale;

        #pragma unroll
        for (int kk = 0; kk < 8; ++kk) {
            int j = kg + 8*kk;
            float p = __expf(s[kk] - mnew);
            l += p;
            const float4* vsr = (const float4*)&vs[j][0];
            #pragma unroll
            for (int d4 = 0; d4 < HID/4; ++d4) {
                float4 vv = vsr[d4];
                acc[4*d4+0] += p*vv.x; acc[4*d4+1] += p*vv.y;
                acc[4*d4+2] += p*vv.z; acc[4*d4+3] += p*vv.w;
            }
        }
        m = mnew;
    }

    // merge 8 lanes per query (butterfly, all lanes end with full state)
    #pragma unroll
    for (int off = 1; off < 8; off <<= 1) {
        float m2 = __shfl_xor(m, off, 64);
        float l2 = __shfl_xor(l, off, 64);
        float M  = fmaxf(m, m2);
        float sa = __expf(m - M), sb = __expf(m2 - M);
        l = l*sa + l2*sb;
        #pragma unroll
        for (int d = 0; d < HID; ++d)
            acc[d] = acc[d]*sa + __shfl_xor(acc[d], off, 64)*sb;
        m = M;
    }

    if ((t & 7) == 0) {
        float rl = 1.f / l;
        #pragma unroll
        for (int d = 0; d < HID; ++d) zs[myq][d] = acc[d] * rl;
    }
    __syncthreads();

    // epilogue: out[b][c][n] = x + wp @ z + bp
    const int j  = t & 63;
    const int c0 = t >> 6;   // 0..7
    #pragma unroll
    for (int ci = 0; ci < 8; ++ci) {
        int c = c0*8 + ci;    // uniform per wave -> wps broadcast
        float sacc = bps[c];
        #pragma unroll
        for (int h = 0; h < HID; ++h) sacc += wps[c][h] * zs[j][h];
        size_t gi = ((size_t)(b*CC + c)) * NN + q0 + j;
        out[gi] = x[gi] + sacc;
    }
}

extern "C" void kernel_launch(void* const* d_in, const int* in_sizes, int n_in,
                              void* d_out, int out_size, void* d_ws, size_t ws_size,
                              hipStream_t stream) {
    const float* x  = (const float*)d_in[0];
    const float* wq = (const float*)d_in[1];
    const float* bq = (const float*)d_in[2];
    const float* wk = (const float*)d_in[3];
    const float* bk = (const float*)d_in[4];
    const float* wv = (const float*)d_in[5];
    const float* bv = (const float*)d_in[6];
    const float* wp = (const float*)d_in[7];
    const float* bp = (const float*)d_in[8];
    float* out = (float*)d_out;

    float* q = (float*)d_ws;                  // [B][N][HID]
    float* k = q + (size_t)BB*NN*HID;
    float* v = k + (size_t)BB*NN*HID;

    qkv_kernel<<<dim3(BB*64), dim3(256), 0, stream>>>(x, wq, bq, wk, bk, wv, bv, q, k, v);
    attn_kernel<<<dim3(BB*64), dim3(512), 0, stream>>>(q, k, v, x, wp, bp, out);
}

// Round 2
// 99.970 us; speedup vs baseline: 3.8923x; 3.8923x over previous
//
#include <hip/hip_runtime.h>
#include <hip/hip_bf16.h>
#include <math.h>

#define BB 4
#define CC 64
#define HID 32
#define NN 4096

typedef short sh4 __attribute__((ext_vector_type(4)));
typedef short sh8 __attribute__((ext_vector_type(8)));
typedef float f4v __attribute__((ext_vector_type(4)));

#define MFMA16(A,B,C) __builtin_amdgcn_mfma_f32_16x16x16bf16_1k(A,B,C,0,0,0)

__device__ __forceinline__ short f2b(float f) {
    __hip_bfloat16 h = __float2bfloat16(f);
    union { __hip_bfloat16 hb; short s; } u; u.hb = h; return u.s;
}

// ---------------------------------------------------------------------------
// Kernel A: QKV projection -> bf16 Q[n][32], K[n][32], Vt[32][n] (per batch)
// ---------------------------------------------------------------------------
__global__ __launch_bounds__(256) void qkv_kernel(
    const float* __restrict__ x,
    const float* __restrict__ wq, const float* __restrict__ bq,
    const float* __restrict__ wk, const float* __restrict__ bk,
    const float* __restrict__ wv, const float* __restrict__ bv,
    short* __restrict__ Qw, short* __restrict__ Kw, short* __restrict__ Vtw)
{
    __shared__ float xs[CC][68];   // x[c][j] tile, pad 68 (272B row, 16B-aligned)
    __shared__ float ws[96][68];   // wq|wk|wv rows
    __shared__ float bs[96];

    const int t  = threadIdx.x;
    const int b  = blockIdx.x >> 6;
    const int n0 = (blockIdx.x & 63) << 6;

    #pragma unroll
    for (int kl = 0; kl < 4; ++kl) {
        int idx = t + 256*kl;
        int c = idx >> 4, j4 = (idx & 15) << 2;
        *(f4v*)&xs[c][j4] = *(const f4v*)(x + ((size_t)(b*CC + c))*NN + n0 + j4);
    }
    #pragma unroll
    for (int kl = 0; kl < 6; ++kl) {
        int idx = t + 256*kl;
        int r = idx >> 4, c4 = (idx & 15) << 2;
        const float* src = (r < 32) ? (wq + r*CC + c4)
                         : (r < 64) ? (wk + (r-32)*CC + c4)
                                    : (wv + (r-64)*CC + c4);
        *(f4v*)&ws[r][c4] = *(const f4v*)src;
    }
    if (t < 96) bs[t] = (t < 32) ? bq[t] : (t < 64) ? bk[t-32] : bv[t-64];
    __syncthreads();

    const int hg = t >> 3;        // 0..31: hid row (same for q,k,v)
    const int j0 = (t & 7) << 3;  // 8 spatial cols

    float aq[8], ak[8], av[8];
    #pragma unroll
    for (int jj = 0; jj < 8; ++jj) { aq[jj]=bs[hg]; ak[jj]=bs[32+hg]; av[jj]=bs[64+hg]; }

    #pragma unroll
    for (int cs = 0; cs < 16; ++cs) {
        f4v wqv = *(f4v*)&ws[hg][cs*4];
        f4v wkv = *(f4v*)&ws[32+hg][cs*4];
        f4v wvv = *(f4v*)&ws[64+hg][cs*4];
        #pragma unroll
        for (int cc = 0; cc < 4; ++cc) {
            f4v x0 = *(f4v*)&xs[cs*4+cc][j0];
            f4v x1 = *(f4v*)&xs[cs*4+cc][j0+4];
            #pragma unroll
            for (int jj = 0; jj < 4; ++jj) {
                aq[jj] += wqv[cc]*x0[jj]; aq[jj+4] += wqv[cc]*x1[jj];
                ak[jj] += wkv[cc]*x0[jj]; ak[jj+4] += wkv[cc]*x1[jj];
                av[jj] += wvv[cc]*x0[jj]; av[jj+4] += wvv[cc]*x1[jj];
            }
        }
    }

    const size_t nb = (size_t)b*NN + n0 + j0;
    short* qp = Qw + nb*HID + hg;
    short* kp = Kw + nb*HID + hg;
    #pragma unroll
    for (int jj = 0; jj < 8; ++jj) {
        qp[jj*HID] = f2b(aq[jj]);
        kp[jj*HID] = f2b(ak[jj]);
    }
    sh8 vv;
    #pragma unroll
    for (int jj = 0; jj < 8; ++jj) vv[jj] = f2b(av[jj]);
    *(sh8*)(Vtw + ((size_t)b*HID + hg)*NN + n0 + j0) = vv;
}

// ---------------------------------------------------------------------------
// Kernel B: MFMA flash attention + projection + residual.
// 256 blocks x 512 thr (8 waves): wave = (q-tile 16 rows, key half 2048).
// Swapped QK^T: S^T = mfma(K, Q^T) -> score layout == PV B-operand layout.
// ---------------------------------------------------------------------------
__global__ __launch_bounds__(512) void attn_kernel(
    const short* __restrict__ Qw, const short* __restrict__ Kw,
    const short* __restrict__ Vtw, const float* __restrict__ x,
    const float* __restrict__ wp, const float* __restrict__ bp,
    float* __restrict__ out)
{
    __shared__ float zr[4][32][17];
    __shared__ float lr[4][16];

    const int t    = threadIdx.x;
    const int b    = blockIdx.x >> 6;
    const int q0   = (blockIdx.x & 63) << 6;
    const int lane = t & 63;
    const int wave = t >> 6;
    const int g    = (lane >> 4) & 3;   // 4-lane-group row block
    const int qi   = lane & 15;
    const int qt   = wave & 3;          // query 16-tile within block
    const int half = wave >> 2;         // key half

    // Q^T B-fragment (held all kernel): B[k=4g+i][q=qi] = Q[q][4g+i]
    const short* Qb = Qw + ((size_t)b*NN + q0 + qt*16 + qi)*HID + 4*g;
    const sh4 qlo = *(const sh4*)Qb;
    const sh4 qhi = *(const sh4*)(Qb + 16);

    const short* kp  = Kw  + ((size_t)b*NN  + half*2048 + qi)*HID + 4*g;
    const short* vp0 = Vtw + ((size_t)b*HID + qi)*NN + half*2048 + 4*g;
    const short* vp1 = vp0 + 16*NN;

    f4v z0 = {0.f,0.f,0.f,0.f}, z1 = {0.f,0.f,0.f,0.f};
    const f4v zero4 = {0.f,0.f,0.f,0.f};
    float lacc = 0.f;

    #pragma unroll 2
    for (int it = 0; it < 64; ++it) {
        sh4 a0 = *(const sh4*)(kp);         // keys T0, dims 0-15
        sh4 a1 = *(const sh4*)(kp + 16);    // keys T0, dims 16-31
        sh4 a2 = *(const sh4*)(kp + 512);   // keys T1 (+16 rows)
        sh4 a3 = *(const sh4*)(kp + 528);
        sh4 v0 = *(const sh4*)(vp0);        // d 0-15, keys T0
        sh4 v1 = *(const sh4*)(vp0 + 16);   // d 0-15, keys T1
        sh4 v2 = *(const sh4*)(vp1);        // d 16-31, keys T0
        sh4 v3 = *(const sh4*)(vp1 + 16);

        f4v s0 = MFMA16(a0, qlo, zero4);
        s0 = MFMA16(a1, qhi, s0);           // S^T[key=4g+r][q=qi], keys T0
        f4v s1 = MFMA16(a2, qlo, zero4);
        s1 = MFMA16(a3, qhi, s1);           // keys T1

        float e0=__expf(s0[0]), e1=__expf(s0[1]), e2=__expf(s0[2]), e3=__expf(s0[3]);
        float f0=__expf(s1[0]), f1=__expf(s1[1]), f2=__expf(s1[2]), f3=__expf(s1[3]);
        lacc += ((e0+e1)+(e2+e3)) + ((f0+f1)+(f2+f3));

        sh4 p0, p1;   // P^T B-fragment == score C/D layout, in-lane
        p0[0]=f2b(e0); p0[1]=f2b(e1); p0[2]=f2b(e2); p0[3]=f2b(e3);
        p1[0]=f2b(f0); p1[1]=f2b(f1); p1[2]=f2b(f2); p1[3]=f2b(f3);

        z0 = MFMA16(v0, p0, z0);            // Z^T[d 0-15][q]
        z1 = MFMA16(v2, p0, z1);            // Z^T[d 16-31][q]
        z0 = MFMA16(v1, p1, z0);
        z1 = MFMA16(v3, p1, z1);

        kp += 1024; vp0 += 32; vp1 += 32;
    }

    // softmax denominator: sum across the 4 lane-groups of this query column
    lacc += __shfl_xor(lacc, 16, 64);
    lacc += __shfl_xor(lacc, 32, 64);

    if (half == 1) {
        #pragma unroll
        for (int r = 0; r < 4; ++r) {
            zr[qt][4*g + r][qi]      = z0[r];
            zr[qt][16 + 4*g + r][qi] = z1[r];
        }
        if (g == 0) lr[qt][qi] = lacc;
    }
    __syncthreads();

    if (half == 0) {
        float inv = 1.0f / (lacc + lr[qt][qi]);
        sh4 pz0, pz1;   // normalized z as PV-identity bf16 B-fragment
        #pragma unroll
        for (int r = 0; r < 4; ++r) {
            float za = (z0[r] + zr[qt][4*g + r][qi]) * inv;
            float zb = (z1[r] + zr[qt][16 + 4*g + r][qi]) * inv;
            pz0[r] = f2b(za); pz1[r] = f2b(zb);
        }
        const int qcol = q0 + qt*16 + qi;
        #pragma unroll
        for (int ct = 0; ct < 4; ++ct) {
            const float* wrow = wp + (ct*16 + qi)*HID + 4*g;
            f4v wa = *(const f4v*)(wrow);        // h 0-15 chunk
            f4v wb = *(const f4v*)(wrow + 16);   // h 16-31 chunk
            sh4 af0, af1;
            #pragma unroll
            for (int i = 0; i < 4; ++i) { af0[i] = f2b(wa[i]); af1[i] = f2b(wb[i]); }
            f4v cacc;
            #pragma unroll
            for (int r = 0; r < 4; ++r) {
                int c = ct*16 + 4*g + r;
                cacc[r] = x[((size_t)(b*CC + c))*NN + qcol] + bp[c];
            }
            cacc = MFMA16(af0, pz0, cacc);
            cacc = MFMA16(af1, pz1, cacc);
            #pragma unroll
            for (int r = 0; r < 4; ++r) {
                int c = ct*16 + 4*g + r;
                out[((size_t)(b*CC + c))*NN + qcol] = cacc[r];
            }
        }
    }
}

extern "C" void kernel_launch(void* const* d_in, const int* in_sizes, int n_in,
                              void* d_out, int out_size, void* d_ws, size_t ws_size,
                              hipStream_t stream) {
    const float* x  = (const float*)d_in[0];
    const float* wq = (const float*)d_in[1];
    const float* bq = (const float*)d_in[2];
    const float* wk = (const float*)d_in[3];
    const float* bk = (const float*)d_in[4];
    const float* wv = (const float*)d_in[5];
    const float* bv = (const float*)d_in[6];
    const float* wp = (const float*)d_in[7];
    const float* bp = (const float*)d_in[8];

    short* Qw  = (short*)d_ws;                       // bf16 [B][N][HID]
    short* Kw  = Qw + (size_t)BB*NN*HID;             // bf16 [B][N][HID]
    short* Vtw = Kw + (size_t)BB*NN*HID;             // bf16 [B][HID][N]

    qkv_kernel<<<dim3(256), dim3(256), 0, stream>>>(x, wq, bq, wk, bk, wv, bv, Qw, Kw, Vtw);
    attn_kernel<<<dim3(256), dim3(512), 0, stream>>>(Qw, Kw, Vtw, x, wp, bp, (float*)d_out);
}

// Round 3
// 39.569 us; speedup vs baseline: 9.8339x; 2.5265x over previous
//
#include <hip/hip_runtime.h>
#include <hip/hip_bf16.h>
#include <math.h>

#define BB 4
#define CC 64
#define HID 32
#define NN 4096

typedef short sh4 __attribute__((ext_vector_type(4)));
typedef short sh8 __attribute__((ext_vector_type(8)));
typedef float f4v __attribute__((ext_vector_type(4)));

#define MFMA32(A,B,C) __builtin_amdgcn_mfma_f32_16x16x32_bf16(A,B,C,0,0,0)

__device__ __forceinline__ short f2b(float f) {
    __hip_bfloat16 h = __float2bfloat16(f);
    union { __hip_bfloat16 hb; short s; } u; u.hb = h; return u.s;
}

// ---------------------------------------------------------------------------
// Kernel A: QKV projection -> bf16 Q[n][32], K[n][32], Vtp[32][n-permuted]
// V^T keys are stored permuted within each 32-key block:
//   pos(key) = 8*((key>>2)&3) + (key&3) + 4*(key>>4)
// so the PV A-fragment (k-order forced by score C/D layout) is contiguous 16B.
// ---------------------------------------------------------------------------
__global__ __launch_bounds__(512) void qkv_kernel(
    const float* __restrict__ x,
    const float* __restrict__ wq, const float* __restrict__ bq,
    const float* __restrict__ wk, const float* __restrict__ bk,
    const float* __restrict__ wv, const float* __restrict__ bv,
    short* __restrict__ Qw, short* __restrict__ Kw, short* __restrict__ Vtp)
{
    __shared__ float xs[64][80];   // pad 80: 16l banks -> 2-way max (free)
    __shared__ float ws[96][80];
    __shared__ float bs[96];

    const int t  = threadIdx.x;
    const int b  = blockIdx.x >> 6;
    const int n0 = (blockIdx.x & 63) << 6;

    #pragma unroll
    for (int kl = 0; kl < 2; ++kl) {
        int idx = t + 512*kl;               // 0..1023
        int c = idx >> 4, j4 = (idx & 15) << 2;
        *(f4v*)&xs[c][j4] = *(const f4v*)(x + ((size_t)(b*CC + c))*NN + n0 + j4);
    }
    #pragma unroll
    for (int kl = 0; kl < 3; ++kl) {
        int idx = t + 512*kl;               // 0..1535
        int r = idx >> 4, c4 = (idx & 15) << 2;
        const float* src = (r < 32) ? (wq + r*CC + c4)
                         : (r < 64) ? (wk + (r-32)*CC + c4)
                                    : (wv + (r-64)*CC + c4);
        *(f4v*)&ws[r][c4] = *(const f4v*)src;
    }
    if (t < 96) bs[t] = (t < 32) ? bq[t] : (t < 64) ? bk[t-32] : bv[t-64];
    __syncthreads();

    const int hg = t & 31;          // hid row, lane-contiguous -> coalesced q/k
    const int j0 = (t >> 5) << 2;   // 4 spatial cols

    float aq[4], ak[4], av[4];
    #pragma unroll
    for (int jj = 0; jj < 4; ++jj) { aq[jj]=bs[hg]; ak[jj]=bs[32+hg]; av[jj]=bs[64+hg]; }

    #pragma unroll
    for (int cs = 0; cs < 16; ++cs) {
        f4v wqv = *(f4v*)&ws[hg][cs*4];
        f4v wkv = *(f4v*)&ws[32+hg][cs*4];
        f4v wvv = *(f4v*)&ws[64+hg][cs*4];
        #pragma unroll
        for (int cc = 0; cc < 4; ++cc) {
            f4v xv = *(f4v*)&xs[cs*4+cc][j0];
            #pragma unroll
            for (int jj = 0; jj < 4; ++jj) {
                aq[jj] += wqv[cc]*xv[jj];
                ak[jj] += wkv[cc]*xv[jj];
                av[jj] += wvv[cc]*xv[jj];
            }
        }
    }

    const size_t nbase = (size_t)b*NN + n0 + j0;
    #pragma unroll
    for (int jj = 0; jj < 4; ++jj) {
        Qw[(nbase + jj)*HID + hg] = f2b(aq[jj]);
        Kw[(nbase + jj)*HID + hg] = f2b(ak[jj]);
    }
    // permuted V^T store
    const int w0 = j0 & 31, g = (w0 >> 2) & 3, hi = w0 >> 4;
    sh4 vv;
    #pragma unroll
    for (int jj = 0; jj < 4; ++jj) vv[jj] = f2b(av[jj]);
    *(sh4*)(Vtp + ((size_t)b*HID + hg)*NN + n0 + (j0 & ~31) + 8*g + 4*hi) = vv;
}

// ---------------------------------------------------------------------------
// Kernel B: MFMA flash attention + projection + residual.
// 512 blocks x 512 thr: block = 32 queries, wave = one key-eighth (512 keys).
// 16x16x32 MFMA, 16B fragments, depth-1 register prefetch, max-free softmax.
// ---------------------------------------------------------------------------
__global__ __launch_bounds__(512, 4) void attn_kernel(
    const short* __restrict__ Qw, const short* __restrict__ Kw,
    const short* __restrict__ Vtp, const float* __restrict__ x,
    const float* __restrict__ wp, const float* __restrict__ bp,
    float* __restrict__ out)
{
    __shared__ float zr[8][32][33];   // [kq][d][q-in-block]
    __shared__ float lr[8][32];

    const int t    = threadIdx.x;
    const int b    = blockIdx.x >> 7;
    const int q0   = (blockIdx.x & 127) << 5;
    const int lane = t & 63;
    const int kq   = t >> 6;        // key eighth
    const int g    = lane >> 4;     // 0..3
    const int qi   = lane & 15;

    // Q B-fragments: k-order = dims 8g..8g+7 (matches K A-frag order)
    const short* qbase = Qw + ((size_t)b*NN + q0 + qi)*HID + 8*g;
    const sh8 qfA = *(const sh8*)qbase;
    const sh8 qfB = *(const sh8*)(qbase + 16*HID);

    const short* kp = Kw  + ((size_t)b*NN  + kq*512 + qi)*HID + 8*g;
    const short* vp = Vtp + ((size_t)b*HID + qi)*NN + kq*512 + 8*g;

    const f4v zf = {0.f,0.f,0.f,0.f};
    f4v zA0 = zf, zA1 = zf, zB0 = zf, zB1 = zf;
    float lA = 0.f, lB = 0.f;

    sh8 a0 = *(const sh8*)kp;
    sh8 a1 = *(const sh8*)(kp + 512);
    sh8 v0 = *(const sh8*)vp;
    sh8 v1 = *(const sh8*)(vp + 16*NN);

    for (int it = 0; it < 16; ++it) {
        const int nx = (it < 15) ? it + 1 : it;
        const short* kn = kp + nx*1024;
        const short* vn = vp + nx*32;
        sh8 na0 = *(const sh8*)kn;
        sh8 na1 = *(const sh8*)(kn + 512);
        sh8 nv0 = *(const sh8*)vn;
        sh8 nv1 = *(const sh8*)(vn + 16*NN);

        f4v s0A = MFMA32(a0, qfA, zf);
        f4v s1A = MFMA32(a1, qfA, zf);
        f4v s0B = MFMA32(a0, qfB, zf);
        f4v s1B = MFMA32(a1, qfB, zf);

        float eA[8], eB[8];
        #pragma unroll
        for (int r = 0; r < 4; ++r) {
            eA[r]   = __expf(s0A[r]);  eA[4+r] = __expf(s1A[r]);
            eB[r]   = __expf(s0B[r]);  eB[4+r] = __expf(s1B[r]);
        }
        lA += ((eA[0]+eA[1])+(eA[2]+eA[3])) + ((eA[4]+eA[5])+(eA[6]+eA[7]));
        lB += ((eB[0]+eB[1])+(eB[2]+eB[3])) + ((eB[4]+eB[5])+(eB[6]+eB[7]));

        sh8 pA, pB;   // element j: j<4 -> key 4g+j (s0), j>=4 -> key 16+4g+j-4 (s1)
        #pragma unroll
        for (int j = 0; j < 8; ++j) { pA[j] = f2b(eA[j]); pB[j] = f2b(eB[j]); }

        zA0 = MFMA32(v0, pA, zA0);   // d 0-15
        zA1 = MFMA32(v1, pA, zA1);   // d 16-31
        zB0 = MFMA32(v0, pB, zB0);
        zB1 = MFMA32(v1, pB, zB1);

        a0 = na0; a1 = na1; v0 = nv0; v1 = nv1;
    }

    lA += __shfl_xor(lA, 16, 64);  lA += __shfl_xor(lA, 32, 64);
    lB += __shfl_xor(lB, 16, 64);  lB += __shfl_xor(lB, 32, 64);

    #pragma unroll
    for (int r = 0; r < 4; ++r) {
        zr[kq][4*g+r][qi]        = zA0[r];
        zr[kq][16+4*g+r][qi]     = zA1[r];
        zr[kq][4*g+r][16+qi]     = zB0[r];
        zr[kq][16+4*g+r][16+qi]  = zB1[r];
    }
    if (g == 0) { lr[kq][qi] = lA; lr[kq][16+qi] = lB; }
    __syncthreads();

    if (kq < 2) {
        const int q = kq*16 + qi;            // query-in-block this wave merges
        float lm = 0.f;
        #pragma unroll
        for (int kk = 0; kk < 8; ++kk) lm += lr[kk][q];
        f4v zm0 = zf, zm1 = zf;
        #pragma unroll
        for (int kk = 0; kk < 8; ++kk) {
            #pragma unroll
            for (int r = 0; r < 4; ++r) {
                zm0[r] += zr[kk][4*g+r][q];
                zm1[r] += zr[kk][16+4*g+r][q];
            }
        }
        const float inv = 1.f / lm;
        sh8 pz;   // element j: j<4 -> d 4g+j, j>=4 -> d 16+4g+j-4
        #pragma unroll
        for (int r = 0; r < 4; ++r) {
            pz[r]   = f2b(zm0[r]*inv);
            pz[4+r] = f2b(zm1[r]*inv);
        }
        const int qcol = q0 + q;
        #pragma unroll
        for (int ct = 0; ct < 4; ++ct) {
            const float* wrow = wp + (ct*16 + qi)*HID;
            f4v wa = *(const f4v*)(wrow + 4*g);        // d 4g..4g+3
            f4v wb = *(const f4v*)(wrow + 16 + 4*g);   // d 16+4g..
            sh8 af;
            #pragma unroll
            for (int i = 0; i < 4; ++i) { af[i] = f2b(wa[i]); af[4+i] = f2b(wb[i]); }
            f4v cacc;
            #pragma unroll
            for (int r = 0; r < 4; ++r) {
                int c = ct*16 + 4*g + r;
                cacc[r] = x[((size_t)(b*CC + c))*NN + qcol] + bp[c];
            }
            cacc = MFMA32(af, pz, cacc);
            #pragma unroll
            for (int r = 0; r < 4; ++r) {
                int c = ct*16 + 4*g + r;
                out[((size_t)(b*CC + c))*NN + qcol] = cacc[r];
            }
        }
    }
}

extern "C" void kernel_launch(void* const* d_in, const int* in_sizes, int n_in,
                              void* d_out, int out_size, void* d_ws, size_t ws_size,
                              hipStream_t stream) {
    const float* x  = (const float*)d_in[0];
    const float* wq = (const float*)d_in[1];
    const float* bq = (const float*)d_in[2];
    const float* wk = (const float*)d_in[3];
    const float* bk = (const float*)d_in[4];
    const float* wv = (const float*)d_in[5];
    const float* bv = (const float*)d_in[6];
    const float* wp = (const float*)d_in[7];
    const float* bp = (const float*)d_in[8];

    short* Qw  = (short*)d_ws;                       // bf16 [B][N][HID]
    short* Kw  = Qw + (size_t)BB*NN*HID;             // bf16 [B][N][HID]
    short* Vtp = Kw + (size_t)BB*NN*HID;             // bf16 [B][HID][N-permuted]

    qkv_kernel<<<dim3(256), dim3(512), 0, stream>>>(x, wq, bq, wk, bk, wv, bv, Qw, Kw, Vtp);
    attn_kernel<<<dim3(512), dim3(512), 0, stream>>>(Qw, Kw, Vtp, x, wp, bp, (float*)d_out);
}

// Round 4
// 28.523 us; speedup vs baseline: 13.6423x; 1.3873x over previous
//
#include <hip/hip_runtime.h>
#include <hip/hip_bf16.h>
#include <math.h>

#define BB 4
#define CC 64
#define HID 32
#define NN 4096
#define LOG2E 1.44269504088896f

typedef short sh4 __attribute__((ext_vector_type(4)));
typedef short sh8 __attribute__((ext_vector_type(8)));
typedef float f4v __attribute__((ext_vector_type(4)));

#define MFMA32(A,B,C) __builtin_amdgcn_mfma_f32_16x16x32_bf16(A,B,C,0,0,0)

__device__ __forceinline__ short f2b(float f) {
    __hip_bfloat16 h = __float2bfloat16(f);
    union { __hip_bfloat16 hb; short s; } u; u.hb = h; return u.s;
}

// ---------------------------------------------------------------------------
// Kernel A: QKV projection -> bf16 Q[n][32] (pre-scaled by log2(e)),
// K[n][32], Vtp[32][n-permuted].
// V^T keys permuted within each 32-key block: pos(key) = 8*((key>>2)&3)
// + (key&3) + 4*(key>>4)  -> PV A-fragment is one contiguous 16B load.
// ---------------------------------------------------------------------------
__global__ __launch_bounds__(512) void qkv_kernel(
    const float* __restrict__ x,
    const float* __restrict__ wq, const float* __restrict__ bq,
    const float* __restrict__ wk, const float* __restrict__ bk,
    const float* __restrict__ wv, const float* __restrict__ bv,
    short* __restrict__ Qw, short* __restrict__ Kw, short* __restrict__ Vtp)
{
    __shared__ float xs[64][80];
    __shared__ float ws[96][80];
    __shared__ float bs[96];

    const int t  = threadIdx.x;
    const int b  = blockIdx.x >> 6;
    const int n0 = (blockIdx.x & 63) << 6;

    #pragma unroll
    for (int kl = 0; kl < 2; ++kl) {
        int idx = t + 512*kl;
        int c = idx >> 4, j4 = (idx & 15) << 2;
        *(f4v*)&xs[c][j4] = *(const f4v*)(x + ((size_t)(b*CC + c))*NN + n0 + j4);
    }
    #pragma unroll
    for (int kl = 0; kl < 3; ++kl) {
        int idx = t + 512*kl;
        int r = idx >> 4, c4 = (idx & 15) << 2;
        const float* src = (r < 32) ? (wq + r*CC + c4)
                         : (r < 64) ? (wk + (r-32)*CC + c4)
                                    : (wv + (r-64)*CC + c4);
        *(f4v*)&ws[r][c4] = *(const f4v*)src;
    }
    if (t < 96) bs[t] = (t < 32) ? bq[t] : (t < 64) ? bk[t-32] : bv[t-64];
    __syncthreads();

    const int hg = t & 31;
    const int j0 = (t >> 5) << 2;

    float aq[4], ak[4], av[4];
    #pragma unroll
    for (int jj = 0; jj < 4; ++jj) { aq[jj]=bs[hg]; ak[jj]=bs[32+hg]; av[jj]=bs[64+hg]; }

    #pragma unroll
    for (int cs = 0; cs < 16; ++cs) {
        f4v wqv = *(f4v*)&ws[hg][cs*4];
        f4v wkv = *(f4v*)&ws[32+hg][cs*4];
        f4v wvv = *(f4v*)&ws[64+hg][cs*4];
        #pragma unroll
        for (int cc = 0; cc < 4; ++cc) {
            f4v xv = *(f4v*)&xs[cs*4+cc][j0];
            #pragma unroll
            for (int jj = 0; jj < 4; ++jj) {
                aq[jj] += wqv[cc]*xv[jj];
                ak[jj] += wkv[cc]*xv[jj];
                av[jj] += wvv[cc]*xv[jj];
            }
        }
    }

    const size_t nbase = (size_t)b*NN + n0 + j0;
    #pragma unroll
    for (int jj = 0; jj < 4; ++jj) {
        Qw[(nbase + jj)*HID + hg] = f2b(aq[jj] * LOG2E);  // exp2 trick
        Kw[(nbase + jj)*HID + hg] = f2b(ak[jj]);
    }
    const int w0 = j0 & 31, g = (w0 >> 2) & 3, hi = w0 >> 4;
    sh4 vv;
    #pragma unroll
    for (int jj = 0; jj < 4; ++jj) vv[jj] = f2b(av[jj]);
    *(sh4*)(Vtp + ((size_t)b*HID + hg)*NN + n0 + (j0 & ~31) + 8*g + 4*hi) = vv;
}

// ---------------------------------------------------------------------------
// Kernel B: MFMA flash attention + projection + residual.
// 256 blocks x 512 thr: block = 64 queries, wave = one key-eighth (512 keys).
// Per 32-key iter: 8 score MFMA + 8 PV MFMA + 4 denom MFMA, 4x16B loads.
// Softmax: max-free, exp2 (Q pre-scaled), denominator via ones-MFMA.
// ---------------------------------------------------------------------------
__global__ __launch_bounds__(512, 2) void attn_kernel(
    const short* __restrict__ Qw, const short* __restrict__ Kw,
    const short* __restrict__ Vtp, const float* __restrict__ x,
    const float* __restrict__ wp, const float* __restrict__ bp,
    float* __restrict__ out)
{
    __shared__ float zr[4][32][65];   // [slot][d][q]
    __shared__ float lr4[4][64];

    const int t    = threadIdx.x;
    const int b    = blockIdx.x >> 6;
    const int q0   = (blockIdx.x & 63) << 6;
    const int lane = t & 63;
    const int kq   = t >> 6;        // key eighth
    const int g    = lane >> 4;
    const int qi   = lane & 15;

    // 4 Q B-fragments (q-subtiles of 16), k-order dims 8g..8g+7
    const short* qbase = Qw + ((size_t)b*NN + q0 + qi)*HID + 8*g;
    sh8 qf[4];
    #pragma unroll
    for (int S = 0; S < 4; ++S) qf[S] = *(const sh8*)(qbase + S*16*HID);

    const short* kp = Kw  + ((size_t)b*NN  + kq*512 + qi)*HID + 8*g;
    const short* vp = Vtp + ((size_t)b*HID + qi)*NN + kq*512 + 8*g;

    const f4v zf = {0.f,0.f,0.f,0.f};
    f4v z0[4], z1[4], lz[4];
    #pragma unroll
    for (int S = 0; S < 4; ++S) { z0[S] = zf; z1[S] = zf; lz[S] = zf; }

    sh8 ones;
    #pragma unroll
    for (int j = 0; j < 8; ++j) ones[j] = (short)0x3F80;  // bf16 1.0

    sh8 a0 = *(const sh8*)kp;
    sh8 a1 = *(const sh8*)(kp + 512);
    sh8 v0 = *(const sh8*)vp;
    sh8 v1 = *(const sh8*)(vp + 16*NN);

    for (int it = 0; it < 16; ++it) {
        const int nx = (it < 15) ? it + 1 : it;
        const short* kn = kp + nx*1024;
        const short* vn = vp + nx*32;
        sh8 na0 = *(const sh8*)kn;
        sh8 na1 = *(const sh8*)(kn + 512);
        sh8 nv0 = *(const sh8*)vn;
        sh8 nv1 = *(const sh8*)(vn + 16*NN);

        f4v s0[4], s1[4];
        #pragma unroll
        for (int S = 0; S < 4; ++S) {
            s0[S] = MFMA32(a0, qf[S], zf);   // keys tile0 x q-subtile S
            s1[S] = MFMA32(a1, qf[S], zf);   // keys tile1
        }

        sh8 p[4];
        #pragma unroll
        for (int S = 0; S < 4; ++S) {
            float e[8];
            #pragma unroll
            for (int r = 0; r < 4; ++r) {
                e[r]   = __builtin_amdgcn_exp2f(s0[S][r]);
                e[4+r] = __builtin_amdgcn_exp2f(s1[S][r]);
            }
            #pragma unroll
            for (int j = 0; j < 8; ++j) p[S][j] = f2b(e[j]);
        }

        #pragma unroll
        for (int S = 0; S < 4; ++S) {
            z0[S] = MFMA32(v0, p[S], z0[S]);     // d 0-15
            z1[S] = MFMA32(v1, p[S], z1[S]);     // d 16-31
            lz[S] = MFMA32(ones, p[S], lz[S]);   // softmax denominator
        }

        a0 = na0; a1 = na1; v0 = nv0; v1 = nv1;
    }

    // two-stage cross-wave merge: 8 partials -> 4 (LDS RMW) -> 1
    if (kq >= 4) {
        #pragma unroll
        for (int S = 0; S < 4; ++S) {
            #pragma unroll
            for (int r = 0; r < 4; ++r) {
                zr[kq-4][4*g+r][S*16+qi]    = z0[S][r];
                zr[kq-4][16+4*g+r][S*16+qi] = z1[S][r];
            }
            if (g == 0) lr4[kq-4][S*16+qi] = lz[S][0];
        }
    }
    __syncthreads();
    if (kq < 4) {
        #pragma unroll
        for (int S = 0; S < 4; ++S) {
            #pragma unroll
            for (int r = 0; r < 4; ++r) {
                zr[kq][4*g+r][S*16+qi]    += z0[S][r];
                zr[kq][16+4*g+r][S*16+qi] += z1[S][r];
            }
            if (g == 0) lr4[kq][S*16+qi] += lz[S][0];
        }
    }
    __syncthreads();

    if (kq < 4) {
        const int q = kq*16 + qi;
        float lm = (lr4[0][q] + lr4[1][q]) + (lr4[2][q] + lr4[3][q]);
        f4v zm0 = zf, zm1 = zf;
        #pragma unroll
        for (int j = 0; j < 4; ++j) {
            #pragma unroll
            for (int r = 0; r < 4; ++r) {
                zm0[r] += zr[j][4*g+r][q];
                zm1[r] += zr[j][16+4*g+r][q];
            }
        }
        const float inv = 1.f / lm;
        sh8 pz;
        #pragma unroll
        for (int r = 0; r < 4; ++r) {
            pz[r]   = f2b(zm0[r]*inv);
            pz[4+r] = f2b(zm1[r]*inv);
        }
        const int qcol = q0 + q;
        #pragma unroll
        for (int ct = 0; ct < 4; ++ct) {
            const float* wrow = wp + (ct*16 + qi)*HID;
            f4v wa = *(const f4v*)(wrow + 4*g);
            f4v wb = *(const f4v*)(wrow + 16 + 4*g);
            sh8 af;
            #pragma unroll
            for (int i = 0; i < 4; ++i) { af[i] = f2b(wa[i]); af[4+i] = f2b(wb[i]); }
            f4v cacc;
            #pragma unroll
            for (int r = 0; r < 4; ++r) {
                int c = ct*16 + 4*g + r;
                cacc[r] = x[((size_t)(b*CC + c))*NN + qcol] + bp[c];
            }
            cacc = MFMA32(af, pz, cacc);
            #pragma unroll
            for (int r = 0; r < 4; ++r) {
                int c = ct*16 + 4*g + r;
                out[((size_t)(b*CC + c))*NN + qcol] = cacc[r];
            }
        }
    }
}

extern "C" void kernel_launch(void* const* d_in, const int* in_sizes, int n_in,
                              void* d_out, int out_size, void* d_ws, size_t ws_size,
                              hipStream_t stream) {
    const float* x  = (const float*)d_in[0];
    const float* wq = (const float*)d_in[1];
    const float* bq = (const float*)d_in[2];
    const float* wk = (const float*)d_in[3];
    const float* bk = (const float*)d_in[4];
    const float* wv = (const float*)d_in[5];
    const float* bv = (const float*)d_in[6];
    const float* wp = (const float*)d_in[7];
    const float* bp = (const float*)d_in[8];

    short* Qw  = (short*)d_ws;                       // bf16 [B][N][HID], pre-scaled by log2(e)
    short* Kw  = Qw + (size_t)BB*NN*HID;             // bf16 [B][N][HID]
    short* Vtp = Kw + (size_t)BB*NN*HID;             // bf16 [B][HID][N-permuted]

    qkv_kernel<<<dim3(256), dim3(512), 0, stream>>>(x, wq, bq, wk, bk, wv, bv, Qw, Kw, Vtp);
    attn_kernel<<<dim3(256), dim3(512), 0, stream>>>(Qw, Kw, Vtp, x, wp, bp, (float*)d_out);
}